// Round 11
// baseline (276.806 us; speedup 1.0000x reference)
//
#include <hip/hip_runtime.h>
#include <hip/hip_bf16.h>

// ---------------------------------------------------------------------------
// HINormer forward, bf16+MFMA multi-kernel (R11).
// R10 -> R11: GEMM tile NPB 64->32 (grid 1563 = 6.1 blocks/CU). R10 counters:
// occ 28.8% (grid-starved at 3 blocks/CU), MfmaUtil 1%, VALU 2.8%, HBM 13% --
// pure latency-bound. Lighter tiles double resident waves; W stays global
// (bfrag straight from L2-hot pre-transposed wt).
// ---------------------------------------------------------------------------

typedef __attribute__((ext_vector_type(8))) short short8;   // 8 bf16
typedef __attribute__((ext_vector_type(4))) float f32x4;
typedef unsigned short u16;

__device__ __forceinline__ float bf2f(u16 u) {
  union { float f; unsigned int i; } v; v.i = (unsigned int)u << 16; return v.f;
}
__device__ __forceinline__ u16 f2bf(float f) {
  union { float f; unsigned int i; } v; v.f = f;
  return (u16)((v.i + 0x7FFF + ((v.i >> 16) & 1)) >> 16);
}

#define NPB 32
#define SWZ(row, byte) ((byte) ^ (((row) & 15) << 4))

// ---- P0: weight transpose/cast + zero ecnt/counter -------------------------
__global__ void k_prep(const float* __restrict__ fcW, const float* __restrict__ gcnW,
                       u16* __restrict__ wt, int* __restrict__ ecnt,
                       int* __restrict__ cnt, int T, int wt_total, int n) {
  const int gt = blockIdx.x * 256 + threadIdx.x;
  const int GT = gridDim.x * 256;
  for (int i = gt; i < wt_total; i += GT) {
    int m = i >> 14, dk = i & 16383, d = dk >> 7, k = dk & 127;
    const float* src = (m < T) ? (fcW + ((size_t)m << 14)) : (gcnW + ((size_t)(m - T) << 14));
    wt[i] = f2bf(src[k * 128 + d]);
  }
  for (int i = gt; i < n; i += GT) ecnt[i] = 0;
  if (gt == 0) *cnt = 0;
}

// stage a [32 x 128] bf16 tile into swizzled LDS; rows >= rows_valid zeroed.
// 256 threads: 8 threads/row, 32B each.
__device__ __forceinline__ void stage_tile_bf16(char* smem, const u16* __restrict__ gsrc,
                                                int rows_valid, int t) {
  int row = t >> 3;
  int h = (t & 7) * 16;
  int byte0 = row * 256 + h * 2;
  if (row < rows_valid) {
    const u16* src = gsrc + (size_t)row * 128 + h;
#pragma unroll
    for (int j = 0; j < 2; ++j) {
      short8 v = *(const short8*)(src + j * 8);
      *(short8*)(smem + SWZ(row, byte0 + j * 16)) = v;
    }
  } else {
    short8 z = (short8){0, 0, 0, 0, 0, 0, 0, 0};
#pragma unroll
    for (int j = 0; j < 2; ++j)
      *(short8*)(smem + SWZ(row, byte0 + j * 16)) = z;
  }
}

// 4 waves; wave w covers output cols [w*32, w*32+32). B-fragments loaded
// directly from global wt (pre-transposed bf16, L2-resident). A from LDS.
__device__ __forceinline__ void mfma_core32_g(const char* xs, const u16* __restrict__ wtg,
                                              int t, f32x4 acc[2][2]) {
  const int lane = t & 63, w = t >> 6;
  const int lr = lane & 15, lk = lane >> 4;
  short8 bfrag[4][2];
#pragma unroll
  for (int ks = 0; ks < 4; ++ks)
#pragma unroll
    for (int ch = 0; ch < 2; ++ch) {
      int row = w * 32 + ch * 16 + lr;
      bfrag[ks][ch] = *(const short8*)(wtg + (size_t)row * 128 + ks * 32 + lk * 8);
    }
#pragma unroll
  for (int ks = 0; ks < 4; ++ks) {
    int kb = ks * 64 + lk * 16;
    short8 a[2];
#pragma unroll
    for (int rg = 0; rg < 2; ++rg) {
      int row = rg * 16 + lr;
      a[rg] = *(const short8*)(xs + SWZ(row, row * 256 + kb));
    }
#pragma unroll
    for (int rg = 0; rg < 2; ++rg)
#pragma unroll
      for (int ch = 0; ch < 2; ++ch)
        acc[rg][ch] = __builtin_amdgcn_mfma_f32_16x16x32_bf16(a[rg], bfrag[ks][ch],
                                                              acc[rg][ch], 0, 0, 0);
  }
}

// ---- k_fc (+ degree count piggyback) ---------------------------------------
__global__ __launch_bounds__(256) void k_fc(const float* __restrict__ x,
                                            const int* __restrict__ node_type,
                                            const u16* __restrict__ wt_fc,
                                            const float* __restrict__ fcB,
                                            u16* __restrict__ gh, int n_nodes,
                                            const int* __restrict__ col,
                                            int* __restrict__ ecnt, int e_edges) {
  __shared__ char smem_xs[8192];
  const int t = threadIdx.x;
  const int nbase = blockIdx.x * NPB;
  const int nend = min(nbase + NPB, n_nodes);
  const int t0 = node_type[nbase];
  const int t1 = node_type[nend - 1];   // sorted types

  {
    int row = t >> 3;
    int h = (t & 7) * 16;
    int node = nbase + row;
    int byte0 = row * 256 + h * 2;
    if (node < n_nodes) {
      const float4* src = (const float4*)(x + (size_t)node * 128 + h);
#pragma unroll
      for (int j = 0; j < 2; ++j) {
        float4 a4 = src[j * 2], b4 = src[j * 2 + 1];
        u16 tmp[8] = {f2bf(a4.x), f2bf(a4.y), f2bf(a4.z), f2bf(a4.w),
                      f2bf(b4.x), f2bf(b4.y), f2bf(b4.z), f2bf(b4.w)};
        *(short8*)(smem_xs + SWZ(row, byte0 + j * 16)) = *(short8*)tmp;
      }
    } else {
      short8 z = (short8){0, 0, 0, 0, 0, 0, 0, 0};
#pragma unroll
      for (int j = 0; j < 2; ++j)
        *(short8*)(smem_xs + SWZ(row, byte0 + j * 16)) = z;
    }
  }
  __syncthreads();  // xs staged; no further LDS writes -> no more barriers

  const int lane = t & 63, w = t >> 6;
  const int lr = lane & 15, lk = lane >> 4;

  for (int tt = t0; tt <= t1; ++tt) {
    f32x4 acc[2][2];
#pragma unroll
    for (int rg = 0; rg < 2; ++rg)
#pragma unroll
      for (int ch = 0; ch < 2; ++ch) acc[rg][ch] = (f32x4){0.f, 0.f, 0.f, 0.f};
    mfma_core32_g(smem_xs, wt_fc + ((size_t)tt << 14), t, acc);

    float bv0 = fcB[tt * 128 + w * 32 + lr];
    float bv1 = fcB[tt * 128 + w * 32 + 16 + lr];
#pragma unroll
    for (int rg = 0; rg < 2; ++rg) {
#pragma unroll
      for (int reg = 0; reg < 4; ++reg) {
        int node = nbase + rg * 16 + lk * 4 + reg;
        if (node < n_nodes && node_type[node] == tt) {
          gh[(size_t)node * 128 + w * 32 + lr]      = f2bf(acc[rg][0][reg] + bv0);
          gh[(size_t)node * 128 + w * 32 + 16 + lr] = f2bf(acc[rg][1][reg] + bv1);
        }
      }
    }
  }

  // piggyback: in-degree count (independent; consumed next launch)
  const int gt = blockIdx.x * 256 + t;
  const int GT = gridDim.x * 256;
  for (int i = gt; i < e_edges; i += GT) atomicAdd(&ecnt[col[i]], 1);
}

// ---- k_gemm_scale (+ optional CSR fill piggyback) --------------------------
__global__ __launch_bounds__(256) void k_gemm_scale(const u16* __restrict__ ghin,
                                                    const u16* __restrict__ wtg,
                                                    const float* __restrict__ dis,
                                                    u16* __restrict__ xws, int n_nodes,
                                                    const int* __restrict__ row,
                                                    const int* __restrict__ col,
                                                    int* __restrict__ cursor,
                                                    int* __restrict__ edge_row,
                                                    int e_edges, int do_fill) {
  __shared__ char smem_xs[8192];
  const int t = threadIdx.x;
  const int nbase = blockIdx.x * NPB;

  stage_tile_bf16(smem_xs, ghin + (size_t)nbase * 128, min(n_nodes - nbase, NPB), t);
  __syncthreads();

  f32x4 acc[2][2];
#pragma unroll
  for (int rg = 0; rg < 2; ++rg)
#pragma unroll
    for (int ch = 0; ch < 2; ++ch) acc[rg][ch] = (f32x4){0.f, 0.f, 0.f, 0.f};
  mfma_core32_g(smem_xs, wtg, t, acc);

  const int lane = t & 63, w = t >> 6;
  const int lr = lane & 15, lk = lane >> 4;
#pragma unroll
  for (int rg = 0; rg < 2; ++rg) {
#pragma unroll
    for (int reg = 0; reg < 4; ++reg) {
      int node = nbase + rg * 16 + lk * 4 + reg;
      if (node < n_nodes) {
        float s = dis[node];
        xws[(size_t)node * 128 + w * 32 + lr]      = f2bf(acc[rg][0][reg] * s);
        xws[(size_t)node * 128 + w * 32 + 16 + lr] = f2bf(acc[rg][1][reg] * s);
      }
    }
  }

  if (do_fill) {  // piggyback: CSR fill (needs cursor from scan3; feeds gather)
    const int gt = blockIdx.x * 256 + t;
    const int GT = gridDim.x * 256;
    for (int i = gt; i < e_edges; i += GT) {
      int c = col[i];
      int pos = atomicAdd(&cursor[c], 1);
      edge_row[pos] = row[i];
    }
  }
}

// ---- scan1: per-chunk scan + dis; last block scans the partials ------------
__global__ __launch_bounds__(256) void k_scan1(const int* __restrict__ ecnt,
                                               int* __restrict__ scanex,
                                               int* __restrict__ partials,
                                               float* __restrict__ dis,
                                               int* __restrict__ cnt, int n) {
  __shared__ int s[256];
  __shared__ int lastflag;
  const int t = threadIdx.x;
  const int i = blockIdx.x * 256 + t;
  int v = (i < n) ? ecnt[i] : 0;
  s[t] = v;
  __syncthreads();
  for (int off = 1; off < 256; off <<= 1) {
    int add = (t >= off) ? s[t - off] : 0;
    __syncthreads();
    s[t] += add;
    __syncthreads();
  }
  if (i < n) {
    scanex[i] = s[t] - v;
    dis[i] = rsqrtf((float)(v + 1));
  }
  if (t == 255) partials[blockIdx.x] = s[t];
  __threadfence();
  if (t == 0) lastflag = (atomicAdd(cnt, 1) == gridDim.x - 1) ? 1 : 0;
  __syncthreads();
  if (lastflag) {  // last-arriving block: exclusive-scan the partials
    __threadfence();
    int np = gridDim.x;
    int pv = (t < np) ? partials[t] : 0;
    s[t] = pv;
    __syncthreads();
    for (int off = 1; off < 256; off <<= 1) {
      int add = (t >= off) ? s[t - off] : 0;
      __syncthreads();
      s[t] += add;
      __syncthreads();
    }
    if (t < np) partials[t] = s[t] - pv;
  }
}

__global__ void k_scan3(const int* __restrict__ scanex, const int* __restrict__ partials,
                        int* __restrict__ col_ptr, int* __restrict__ cursor,
                        int n, int e_total) {
  int i = blockIdx.x * 256 + threadIdx.x;
  if (i < n) {
    int p = scanex[i] + partials[i >> 8];
    col_ptr[i] = p;
    cursor[i] = p;
  }
  if (i == 0) col_ptr[n] = e_total;
}

// ---- fused gather + finalize ------------------------------------------------
__device__ __forceinline__ void gather_node(int node, const int* __restrict__ col_ptr,
                                            const int* __restrict__ edge_row,
                                            const u16* __restrict__ xws,
                                            const float* __restrict__ dis,
                                            const float* __restrict__ bias,
                                            u16* __restrict__ dst, int lane) {
  const int g = lane & 15;
  const int s = lane >> 4;
  float acc[8] = {0.f, 0.f, 0.f, 0.f, 0.f, 0.f, 0.f, 0.f};
  if (s == 0) {  // self loop
    short8 v = *(const short8*)(xws + (size_t)node * 128 + g * 8);
#pragma unroll
    for (int j = 0; j < 8; ++j) acc[j] = bf2f((u16)v[j]);
  }
  const int e0 = col_ptr[node], e1 = col_ptr[node + 1];
  for (int e = e0 + s; e < e1; e += 4) {
    int r = edge_row[e];
    short8 v = *(const short8*)(xws + (size_t)r * 128 + g * 8);
#pragma unroll
    for (int j = 0; j < 8; ++j) acc[j] += bf2f((u16)v[j]);
  }
#pragma unroll
  for (int j = 0; j < 8; ++j) {
    acc[j] += __shfl_xor(acc[j], 16);
    acc[j] += __shfl_xor(acc[j], 32);
  }
  if (s == 0) {
    float ds = dis[node];
    u16 o[8];
#pragma unroll
    for (int j = 0; j < 8; ++j)
      o[j] = f2bf(fmaxf(acc[j] * ds + bias[g * 8 + j], 0.f));
    *(short8*)(dst + g * 8) = *(short8*)o;
  }
}

__global__ __launch_bounds__(256) void k_gather(const int* __restrict__ col_ptr,
                                                const int* __restrict__ edge_row,
                                                const u16* __restrict__ xws,
                                                const float* __restrict__ dis,
                                                const float* __restrict__ bias,
                                                u16* __restrict__ gh, int n_nodes) {
  const int t = threadIdx.x;
  const int node = blockIdx.x * 4 + (t >> 6);
  if (node >= n_nodes) return;
  gather_node(node, col_ptr, edge_row, xws, dis, bias,
              gh + (size_t)node * 128, t & 63);
}

// ---- last layer: gather only ego nodes, then predict in-kernel -------------
__global__ __launch_bounds__(256) void k_egopred(const int* __restrict__ col_ptr,
                                                 const int* __restrict__ edge_row,
                                                 const u16* __restrict__ xws,
                                                 const float* __restrict__ dis,
                                                 const float* __restrict__ bias,
                                                 const int* __restrict__ seqs,
                                                 const int* __restrict__ label,
                                                 const float* __restrict__ predW,
                                                 const float* __restrict__ predB,
                                                 float* __restrict__ out,
                                                 float* __restrict__ out_label,
                                                 int b_total, int n_classes, int slen) {
  __shared__ u16 buf[4][128];
  const int t = threadIdx.x;
  const int w = t >> 6, lane = t & 63;
  const int b = blockIdx.x * 4 + w;
  int node = -1;
  if (b < b_total) {
    node = seqs[(size_t)b * slen];
    gather_node(node, col_ptr, edge_row, xws, dis, bias, &buf[w][0], lane);
  }
  __syncthreads();
  if (b < b_total) {
    const int c = lane & 15;     // class (n_classes == 16)
    const int q = lane >> 4;     // k-chunk 0..3
    float s = 0.f;
#pragma unroll 8
    for (int k = q * 32; k < q * 32 + 32; ++k)
      s += bf2f(buf[w][k]) * predW[k * n_classes + c];
    s += __shfl_xor(s, 16);
    s += __shfl_xor(s, 32);
    if (q == 0) out[(size_t)b * n_classes + c] = s + predB[c];
    if (lane == 0) out_label[b] = (float)label[node];
  }
}

extern "C" void kernel_launch(void* const* d_in, const int* in_sizes, int n_in,
                              void* d_out, int out_size, void* d_ws, size_t ws_size,
                              hipStream_t stream) {
  const float* x     = (const float*)d_in[0];
  const int*   label = (const int*)d_in[1];
  const int*   seqs  = (const int*)d_in[2];
  const int*   edge  = (const int*)d_in[3];
  const int*   ntype = (const int*)d_in[4];
  const float* fcW   = (const float*)d_in[5];
  const float* fcB   = (const float*)d_in[6];
  const float* gcnW  = (const float*)d_in[7];
  const float* gcnB  = (const float*)d_in[8];
  const float* predW = (const float*)d_in[12];
  const float* predB = (const float*)d_in[13];

  const int n = in_sizes[0] / 128;          // 50000
  const int e = in_sizes[3] / 2;            // 600000
  const int T = in_sizes[5] / (128 * 128);  // 4
  const int L = in_sizes[8] / 128;          // 2
  const int C = in_sizes[13];               // 16
  const int slen = 16;
  const int b_total = in_sizes[2] / slen;   // 2048

  const int* row = edge;
  const int* col = edge + e;

  char* ws = (char*)d_ws;
  const size_t node_bf = (size_t)n * 128 * sizeof(u16);
  u16*   gh      = (u16*)ws;                 ws += node_bf;
  u16*   xws     = (u16*)ws;                 ws += node_bf;
  u16*   wt      = (u16*)ws;                 ws += (size_t)(T + L) * 16384 * 2;
  float* dis     = (float*)ws;               ws += (size_t)n * 4;
  int*   ecnt    = (int*)ws;                 ws += (size_t)n * 4;
  int*   scanex  = (int*)ws;                 ws += (size_t)n * 4;
  int*   col_ptr = (int*)ws;                 ws += (size_t)(n + 16) * 4;
  int*   cursor  = (int*)ws;                 ws += (size_t)n * 4;
  int*   partial = (int*)ws;                 ws += 1024 * 4;
  int*   cnt     = (int*)ws;                 ws += 64;
  int*   edge_row= (int*)ws;                 ws += (size_t)e * 4;

  float* out_logits = (float*)d_out;
  float* out_label  = out_logits + (size_t)b_total * C;

  const int nb = (n + NPB - 1) / NPB;       // 1563
  const int nscan = (n + 255) / 256;        // 196
  const int wt_total = (T + L) * 16384;

  hipLaunchKernelGGL(k_prep, dim3(384), dim3(256), 0, stream,
                     fcW, gcnW, wt, ecnt, cnt, T, wt_total, n);
  hipLaunchKernelGGL(k_fc, dim3(nb), dim3(256), 0, stream,
                     x, ntype, wt, fcB, gh, n, col, ecnt, e);
  hipLaunchKernelGGL(k_scan1, dim3(nscan), dim3(256), 0, stream,
                     ecnt, scanex, partial, dis, cnt, n);
  hipLaunchKernelGGL(k_scan3, dim3(nscan), dim3(256), 0, stream,
                     scanex, partial, col_ptr, cursor, n, e);

  for (int l = 0; l < L; ++l) {
    hipLaunchKernelGGL(k_gemm_scale, dim3(nb), dim3(256), 0, stream,
                       gh, wt + (size_t)(T + l) * 16384, dis, xws, n,
                       row, col, cursor, edge_row, e, (l == 0) ? 1 : 0);
    if (l < L - 1) {
      hipLaunchKernelGGL(k_gather, dim3((n + 3) / 4), dim3(256), 0, stream,
                         col_ptr, edge_row, xws, dis, gcnB + (size_t)l * 128, gh, n);
    } else {
      hipLaunchKernelGGL(k_egopred, dim3((b_total + 3) / 4), dim3(256), 0, stream,
                         col_ptr, edge_row, xws, dis, gcnB + (size_t)l * 128,
                         seqs, label, predW, predB, out_logits, out_label,
                         b_total, C, slen);
    }
  }
}

// Round 13
// 251.073 us; speedup vs baseline: 1.1025x; 1.1025x over previous
//
#include <hip/hip_runtime.h>
#include <hip/hip_bf16.h>

// ---------------------------------------------------------------------------
// HINormer forward, bf16+MFMA multi-kernel (R12).
// Algebraic commutation: (A.diag(dis).gh)@W == A.diag(dis).(gh@W), so each
// layer is gather-first:  agg_c = sum' dis_r*gh_r  ->  gh' = relu((agg@W)*dis_c+b).
// Last layer only needs ego rows => full 50k GEMM of layer 1 replaced by a
// 2048-row tail GEMM fused with pred. GEMM tiles back to R8-proven NPB=128
// with LDS-staged W (tile sweep R8-R11 showed per-block W reuse dominates,
// not occupancy). 8 launches.
// ---------------------------------------------------------------------------

typedef __attribute__((ext_vector_type(8))) short short8;   // 8 bf16
typedef __attribute__((ext_vector_type(4))) float f32x4;
typedef unsigned short u16;

__device__ __forceinline__ float bf2f(u16 u) {
  union { float f; unsigned int i; } v; v.i = (unsigned int)u << 16; return v.f;
}
__device__ __forceinline__ u16 f2bf(float f) {
  union { float f; unsigned int i; } v; v.f = f;
  return (u16)((v.i + 0x7FFF + ((v.i >> 16) & 1)) >> 16);
}

#define NPB 128
#define SWZ(row, byte) ((byte) ^ (((row) & 15) << 4))

// ---- P0: weight transpose/cast + zero ecnt/slot/cnt ------------------------
__global__ void k_prep(const float* __restrict__ fcW, const float* __restrict__ gcnW,
                       u16* __restrict__ wt, int* __restrict__ ecnt,
                       int* __restrict__ slot, int* __restrict__ cnt,
                       int T, int wt_total, int n) {
  const int gt = blockIdx.x * 256 + threadIdx.x;
  const int GT = gridDim.x * 256;
  for (int i = gt; i < wt_total; i += GT) {
    int m = i >> 14, dk = i & 16383, d = dk >> 7, k = dk & 127;
    const float* src = (m < T) ? (fcW + ((size_t)m << 14)) : (gcnW + ((size_t)(m - T) << 14));
    wt[i] = f2bf(src[k * 128 + d]);
  }
  for (int i = gt; i < n; i += GT) { ecnt[i] = 0; slot[i] = 0; }
  if (gt == 0) *cnt = 0;
}

// stage a [128 x 128] bf16 tile into swizzled LDS; rows >= rows_valid zeroed.
// 256 threads: 2 threads/row, 128B each.
__device__ __forceinline__ void stage_tile_bf16(char* smem, const u16* __restrict__ gsrc,
                                                int rows_valid, int t) {
  int row = t >> 1;
  int h = (t & 1) * 64;
  int byte0 = row * 256 + h * 2;
  if (row < rows_valid) {
    const u16* src = gsrc + (size_t)row * 128 + h;
#pragma unroll
    for (int j = 0; j < 8; ++j) {
      short8 v = *(const short8*)(src + j * 8);
      *(short8*)(smem + SWZ(row, byte0 + j * 16)) = v;
    }
  } else {
    short8 z = (short8){0, 0, 0, 0, 0, 0, 0, 0};
#pragma unroll
    for (int j = 0; j < 8; ++j)
      *(short8*)(smem + SWZ(row, byte0 + j * 16)) = z;
  }
}

// 4 waves; wave w covers output cols [w*32, w*32+32). B preloaded from LDS
// (32 VGPR), A streamed from LDS: 8 ds_read : 16 MFMA per k-slice.
__device__ __forceinline__ void mfma_core128(const char* xs, const char* wt, int t,
                                             f32x4 acc[8][2]) {
  const int lane = t & 63, w = t >> 6;
  const int lr = lane & 15, lk = lane >> 4;
  short8 bfrag[4][2];
#pragma unroll
  for (int ks = 0; ks < 4; ++ks) {
    int kb = ks * 64 + lk * 16;
#pragma unroll
    for (int ch = 0; ch < 2; ++ch) {
      int row = w * 32 + ch * 16 + lr;
      bfrag[ks][ch] = *(const short8*)(wt + SWZ(row, row * 256 + kb));
    }
  }
#pragma unroll
  for (int ks = 0; ks < 4; ++ks) {
    int kb = ks * 64 + lk * 16;
    short8 a[8];
#pragma unroll
    for (int rg = 0; rg < 8; ++rg) {
      int row = rg * 16 + lr;
      a[rg] = *(const short8*)(xs + SWZ(row, row * 256 + kb));
    }
#pragma unroll
    for (int rg = 0; rg < 8; ++rg)
#pragma unroll
      for (int ch = 0; ch < 2; ++ch)
        acc[rg][ch] = __builtin_amdgcn_mfma_f32_16x16x32_bf16(a[rg], bfrag[ks][ch],
                                                              acc[rg][ch], 0, 0, 0);
  }
}

// ---- k_fc (+ degree count piggyback): gh0 = x @ fcW[type] + fcB ------------
__global__ __launch_bounds__(256) void k_fc(const float* __restrict__ x,
                                            const int* __restrict__ node_type,
                                            const u16* __restrict__ wt_fc,
                                            const float* __restrict__ fcB,
                                            u16* __restrict__ gh, int n_nodes,
                                            const int* __restrict__ col,
                                            int* __restrict__ ecnt, int e_edges) {
  __shared__ char smem[65536];
  char* smem_xs = smem;
  char* smem_wt = smem + 32768;
  const int t = threadIdx.x;
  const int nbase = blockIdx.x * NPB;
  const int nend = min(nbase + NPB, n_nodes);
  const int t0 = node_type[nbase];
  const int t1 = node_type[nend - 1];   // sorted types

  {
    int row = t >> 1;
    int h = (t & 1) * 64;
    int node = nbase + row;
    int byte0 = row * 256 + h * 2;
    if (node < n_nodes) {
      const float4* src = (const float4*)(x + (size_t)node * 128 + h);
#pragma unroll
      for (int j = 0; j < 8; ++j) {
        float4 a4 = src[j * 2], b4 = src[j * 2 + 1];
        u16 tmp[8] = {f2bf(a4.x), f2bf(a4.y), f2bf(a4.z), f2bf(a4.w),
                      f2bf(b4.x), f2bf(b4.y), f2bf(b4.z), f2bf(b4.w)};
        *(short8*)(smem_xs + SWZ(row, byte0 + j * 16)) = *(short8*)tmp;
      }
    } else {
      short8 z = (short8){0, 0, 0, 0, 0, 0, 0, 0};
#pragma unroll
      for (int j = 0; j < 8; ++j)
        *(short8*)(smem_xs + SWZ(row, byte0 + j * 16)) = z;
    }
  }

  const int lane = t & 63, w = t >> 6;
  const int lr = lane & 15, lk = lane >> 4;

  for (int tt = t0; tt <= t1; ++tt) {
    __syncthreads();  // xs staged / prior wt reads done
    stage_tile_bf16(smem_wt, wt_fc + ((size_t)tt << 14), 128, t);
    __syncthreads();

    f32x4 acc[8][2];
#pragma unroll
    for (int rg = 0; rg < 8; ++rg)
#pragma unroll
      for (int ch = 0; ch < 2; ++ch) acc[rg][ch] = (f32x4){0.f, 0.f, 0.f, 0.f};
    mfma_core128(smem_xs, smem_wt, t, acc);

    float bv0 = fcB[tt * 128 + w * 32 + lr];
    float bv1 = fcB[tt * 128 + w * 32 + 16 + lr];
#pragma unroll
    for (int rg = 0; rg < 8; ++rg) {
#pragma unroll
      for (int reg = 0; reg < 4; ++reg) {
        int node = nbase + rg * 16 + lk * 4 + reg;
        if (node < n_nodes && node_type[node] == tt) {
          gh[(size_t)node * 128 + w * 32 + lr]      = f2bf(acc[rg][0][reg] + bv0);
          gh[(size_t)node * 128 + w * 32 + 16 + lr] = f2bf(acc[rg][1][reg] + bv1);
        }
      }
    }
  }

  // piggyback: in-degree count (independent; consumed next launch)
  const int gt = blockIdx.x * 256 + t;
  const int GT = gridDim.x * 256;
  for (int i = gt; i < e_edges; i += GT) atomicAdd(&ecnt[col[i]], 1);
}

// ---- scan1: per-chunk scan + dis; last block scans the partials ------------
__global__ __launch_bounds__(256) void k_scan1(const int* __restrict__ ecnt,
                                               int* __restrict__ scanex,
                                               int* __restrict__ partials,
                                               float* __restrict__ dis,
                                               int* __restrict__ cnt, int n) {
  __shared__ int s[256];
  __shared__ int lastflag;
  const int t = threadIdx.x;
  const int i = blockIdx.x * 256 + t;
  int v = (i < n) ? ecnt[i] : 0;
  s[t] = v;
  __syncthreads();
  for (int off = 1; off < 256; off <<= 1) {
    int add = (t >= off) ? s[t - off] : 0;
    __syncthreads();
    s[t] += add;
    __syncthreads();
  }
  if (i < n) {
    scanex[i] = s[t] - v;
    dis[i] = rsqrtf((float)(v + 1));
  }
  if (t == 255) partials[blockIdx.x] = s[t];
  __threadfence();
  if (t == 0) lastflag = (atomicAdd(cnt, 1) == gridDim.x - 1) ? 1 : 0;
  __syncthreads();
  if (lastflag) {
    __threadfence();
    int np = gridDim.x;
    int pv = (t < np) ? partials[t] : 0;
    s[t] = pv;
    __syncthreads();
    for (int off = 1; off < 256; off <<= 1) {
      int add = (t >= off) ? s[t - off] : 0;
      __syncthreads();
      s[t] += add;
      __syncthreads();
    }
    if (t < np) partials[t] = s[t] - pv;
  }
}

// ---- scan3 + CSR fill (fill uses scanex+partial directly + slot counters) --
__global__ void k_scan3_fill(const int* __restrict__ scanex,
                             const int* __restrict__ partials,
                             int* __restrict__ col_ptr, int* __restrict__ slot,
                             const int* __restrict__ row, const int* __restrict__ col,
                             int* __restrict__ edge_row, int n, int e_total) {
  const int gt = blockIdx.x * 256 + threadIdx.x;
  const int GT = gridDim.x * 256;
  if (gt < n) col_ptr[gt] = scanex[gt] + partials[gt >> 8];
  if (gt == 0) col_ptr[n] = e_total;
  for (int i = gt; i < e_total; i += GT) {
    int c = col[i];
    int base = scanex[c] + partials[c >> 8];
    int pos = base + atomicAdd(&slot[c], 1);
    edge_row[pos] = row[i];
  }
}

// ---- gather with per-edge dis:  dst = gh[node]*dis[node] + sum gh[r]*dis[r]
__device__ __forceinline__ void gather_s(int node, const int* __restrict__ col_ptr,
                                         const int* __restrict__ edge_row,
                                         const u16* __restrict__ gh,
                                         const float* __restrict__ dis,
                                         u16* __restrict__ dst, int lane) {
  const int g = lane & 15;
  const int s = lane >> 4;
  float acc[8] = {0.f, 0.f, 0.f, 0.f, 0.f, 0.f, 0.f, 0.f};
  if (s == 0) {  // self loop
    float ds = dis[node];
    short8 v = *(const short8*)(gh + (size_t)node * 128 + g * 8);
#pragma unroll
    for (int j = 0; j < 8; ++j) acc[j] = bf2f((u16)v[j]) * ds;
  }
  const int e0 = col_ptr[node], e1 = col_ptr[node + 1];
  for (int e = e0 + s; e < e1; e += 4) {
    int r = edge_row[e];
    float dr = dis[r];
    short8 v = *(const short8*)(gh + (size_t)r * 128 + g * 8);
#pragma unroll
    for (int j = 0; j < 8; ++j) acc[j] += bf2f((u16)v[j]) * dr;
  }
#pragma unroll
  for (int j = 0; j < 8; ++j) {
    acc[j] += __shfl_xor(acc[j], 16);
    acc[j] += __shfl_xor(acc[j], 32);
  }
  if (s == 0) {
    u16 o[8];
#pragma unroll
    for (int j = 0; j < 8; ++j) o[j] = f2bf(acc[j]);
    *(short8*)(dst + g * 8) = *(short8*)o;
  }
}

__global__ __launch_bounds__(256) void k_gather(const int* __restrict__ col_ptr,
                                                const int* __restrict__ edge_row,
                                                const u16* __restrict__ gh,
                                                const float* __restrict__ dis,
                                                u16* __restrict__ agg, int n_nodes) {
  const int t = threadIdx.x;
  const int node = blockIdx.x * 4 + (t >> 6);
  if (node >= n_nodes) return;
  gather_s(node, col_ptr, edge_row, gh, dis, agg + (size_t)node * 128, t & 63);
}

__global__ __launch_bounds__(256) void k_gather_ego(const int* __restrict__ col_ptr,
                                                    const int* __restrict__ edge_row,
                                                    const u16* __restrict__ gh,
                                                    const float* __restrict__ dis,
                                                    const int* __restrict__ seqs,
                                                    u16* __restrict__ agg2,
                                                    int b_total, int slen) {
  const int t = threadIdx.x;
  const int b = blockIdx.x * 4 + (t >> 6);
  if (b >= b_total) return;
  int node = seqs[(size_t)b * slen];
  gather_s(node, col_ptr, edge_row, gh, dis, agg2 + (size_t)b * 128, t & 63);
}

// ---- k_gemm: gh' = relu((agg @ W)*dis_c + b) -------------------------------
__global__ __launch_bounds__(256) void k_gemm(const u16* __restrict__ agg,
                                              const u16* __restrict__ wtg,
                                              const float* __restrict__ dis,
                                              const float* __restrict__ bias,
                                              u16* __restrict__ gh, int n_nodes) {
  __shared__ char smem[65536];
  char* smem_xs = smem;
  char* smem_wt = smem + 32768;
  const int t = threadIdx.x;
  const int nbase = blockIdx.x * NPB;

  stage_tile_bf16(smem_xs, agg + (size_t)nbase * 128, min(n_nodes - nbase, NPB), t);
  stage_tile_bf16(smem_wt, wtg, 128, t);
  __syncthreads();

  f32x4 acc[8][2];
#pragma unroll
  for (int rg = 0; rg < 8; ++rg)
#pragma unroll
    for (int ch = 0; ch < 2; ++ch) acc[rg][ch] = (f32x4){0.f, 0.f, 0.f, 0.f};
  mfma_core128(smem_xs, smem_wt, t, acc);

  const int lane = t & 63, w = t >> 6;
  const int lr = lane & 15, lk = lane >> 4;
  float bv0 = bias[w * 32 + lr];
  float bv1 = bias[w * 32 + 16 + lr];
#pragma unroll
  for (int rg = 0; rg < 8; ++rg) {
#pragma unroll
    for (int reg = 0; reg < 4; ++reg) {
      int node = nbase + rg * 16 + lk * 4 + reg;
      if (node < n_nodes) {
        float s = dis[node];
        gh[(size_t)node * 128 + w * 32 + lr] =
            f2bf(fmaxf(acc[rg][0][reg] * s + bv0, 0.f));
        gh[(size_t)node * 128 + w * 32 + 16 + lr] =
            f2bf(fmaxf(acc[rg][1][reg] * s + bv1, 0.f));
      }
    }
  }
}

// ---- k_tail: gh2 = relu((agg2 @ W1)*dis + b) ; out = gh2 @ predW + predB ---
__global__ __launch_bounds__(256) void k_tail(const u16* __restrict__ agg2,
                                              const u16* __restrict__ wt1,
                                              const float* __restrict__ dis,
                                              const float* __restrict__ bias,
                                              const int* __restrict__ seqs,
                                              const int* __restrict__ label,
                                              const float* __restrict__ predW,
                                              const float* __restrict__ predB,
                                              float* __restrict__ out,
                                              float* __restrict__ out_label,
                                              int b_total, int n_classes, int slen) {
  __shared__ char smem_wt[32768];
  __shared__ char smem_xs[8192];     // 32x128 bf16 swizzled
  __shared__ u16 gh2[32 * 128];
  __shared__ int egos[32];
  const int t = threadIdx.x;
  const int b0 = blockIdx.x * 32;

  stage_tile_bf16(smem_wt, wt1, 128, t);
  {  // stage agg2 tile: 32 rows, 8 threads/row, 16B each
    int row = t >> 3;
    int h = (t & 7) * 8;
    int bb = b0 + row;
    short8 v;
    if (bb < b_total) v = *(const short8*)(agg2 + (size_t)bb * 128 + h);
    else v = (short8){0, 0, 0, 0, 0, 0, 0, 0};
    *(short8*)(smem_xs + SWZ(row, row * 256 + h * 2)) = v;
  }
  if (t < 32) egos[t] = (b0 + t < b_total) ? seqs[(size_t)(b0 + t) * slen] : 0;
  __syncthreads();

  const int lane = t & 63, w = t >> 6;
  const int lr = lane & 15, lk = lane >> 4;
  f32x4 acc[2][2];
#pragma unroll
  for (int rg = 0; rg < 2; ++rg)
#pragma unroll
    for (int ch = 0; ch < 2; ++ch) acc[rg][ch] = (f32x4){0.f, 0.f, 0.f, 0.f};
  {
    short8 bfrag[4][2];
#pragma unroll
    for (int ks = 0; ks < 4; ++ks) {
      int kb = ks * 64 + lk * 16;
#pragma unroll
      for (int ch = 0; ch < 2; ++ch) {
        int rowb = w * 32 + ch * 16 + lr;
        bfrag[ks][ch] = *(const short8*)(smem_wt + SWZ(rowb, rowb * 256 + kb));
      }
    }
#pragma unroll
    for (int ks = 0; ks < 4; ++ks) {
      int kb = ks * 64 + lk * 16;
      short8 a[2];
#pragma unroll
      for (int rg = 0; rg < 2; ++rg) {
        int row = rg * 16 + lr;
        a[rg] = *(const short8*)(smem_xs + SWZ(row, row * 256 + kb));
      }
#pragma unroll
      for (int rg = 0; rg < 2; ++rg)
#pragma unroll
        for (int ch = 0; ch < 2; ++ch)
          acc[rg][ch] = __builtin_amdgcn_mfma_f32_16x16x32_bf16(a[rg], bfrag[ks][ch],
                                                                acc[rg][ch], 0, 0, 0);
    }
  }
#pragma unroll
  for (int rg = 0; rg < 2; ++rg) {
#pragma unroll
    for (int reg = 0; reg < 4; ++reg) {
      int row = rg * 16 + lk * 4 + reg;
      float s = dis[egos[row]];
#pragma unroll
      for (int ch = 0; ch < 2; ++ch) {
        int dout = w * 32 + ch * 16 + lr;
        gh2[row * 128 + dout] = f2bf(fmaxf(acc[rg][ch][reg] * s + bias[dout], 0.f));
      }
    }
  }
  __syncthreads();

  for (int idx = t; idx < 32 * n_classes; idx += 256) {
    int row = idx / n_classes, c = idx - (idx / n_classes) * n_classes;
    if (b0 + row >= b_total) continue;
    float s = predB[c];
#pragma unroll 8
    for (int k = 0; k < 128; ++k)
      s += bf2f(gh2[row * 128 + k]) * predW[k * n_classes + c];
    out[(size_t)(b0 + row) * n_classes + c] = s;
    if (c == 0) out_label[b0 + row] = (float)label[egos[row]];
  }
}

extern "C" void kernel_launch(void* const* d_in, const int* in_sizes, int n_in,
                              void* d_out, int out_size, void* d_ws, size_t ws_size,
                              hipStream_t stream) {
  const float* x     = (const float*)d_in[0];
  const int*   label = (const int*)d_in[1];
  const int*   seqs  = (const int*)d_in[2];
  const int*   edge  = (const int*)d_in[3];
  const int*   ntype = (const int*)d_in[4];
  const float* fcW   = (const float*)d_in[5];
  const float* fcB   = (const float*)d_in[6];
  const float* gcnW  = (const float*)d_in[7];
  const float* gcnB  = (const float*)d_in[8];
  const float* predW = (const float*)d_in[12];
  const float* predB = (const float*)d_in[13];

  const int n = in_sizes[0] / 128;          // 50000
  const int e = in_sizes[3] / 2;            // 600000
  const int T = in_sizes[5] / (128 * 128);  // 4
  const int C = in_sizes[13];               // 16
  const int slen = 16;
  const int b_total = in_sizes[2] / slen;   // 2048

  const int* row = edge;
  const int* col = edge + e;

  char* ws = (char*)d_ws;
  const size_t node_bf = (size_t)n * 128 * sizeof(u16);
  u16*   gh      = (u16*)ws;                 ws += node_bf;
  u16*   agg     = (u16*)ws;                 ws += node_bf;
  u16*   agg2    = (u16*)ws;                 ws += (size_t)b_total * 128 * 2;
  u16*   wt      = (u16*)ws;                 ws += (size_t)(T + 2) * 16384 * 2;
  float* dis     = (float*)ws;               ws += (size_t)n * 4;
  int*   ecnt    = (int*)ws;                 ws += (size_t)n * 4;
  int*   scanex  = (int*)ws;                 ws += (size_t)n * 4;
  int*   col_ptr = (int*)ws;                 ws += (size_t)(n + 16) * 4;
  int*   slot    = (int*)ws;                 ws += (size_t)n * 4;
  int*   partial = (int*)ws;                 ws += 1024 * 4;
  int*   cnt     = (int*)ws;                 ws += 64;
  int*   edge_row= (int*)ws;                 ws += (size_t)e * 4;

  float* out_logits = (float*)d_out;
  float* out_label  = out_logits + (size_t)b_total * C;

  const int nb = (n + NPB - 1) / NPB;       // 391
  const int nscan = (n + 255) / 256;        // 196
  const int wt_total = (T + 2) * 16384;

  hipLaunchKernelGGL(k_prep, dim3(384), dim3(256), 0, stream,
                     fcW, gcnW, wt, ecnt, slot, cnt, T, wt_total, n);
  hipLaunchKernelGGL(k_fc, dim3(nb), dim3(256), 0, stream,
                     x, ntype, wt, fcB, gh, n, col, ecnt, e);
  hipLaunchKernelGGL(k_scan1, dim3(nscan), dim3(256), 0, stream,
                     ecnt, scanex, partial, dis, cnt, n);
  hipLaunchKernelGGL(k_scan3_fill, dim3(1024), dim3(256), 0, stream,
                     scanex, partial, col_ptr, slot, row, col, edge_row, n, e);

  // layer 0: gather-first, then GEMM with fused relu/bias/dis epilogue
  hipLaunchKernelGGL(k_gather, dim3((n + 3) / 4), dim3(256), 0, stream,
                     col_ptr, edge_row, gh, dis, agg, n);
  hipLaunchKernelGGL(k_gemm, dim3(nb), dim3(256), 0, stream,
                     agg, wt + (size_t)T * 16384, dis, gcnB, gh, n);

  // layer 1: only ego rows are consumed -> ego gather + fused tail GEMM+pred
  hipLaunchKernelGGL(k_gather_ego, dim3((b_total + 3) / 4), dim3(256), 0, stream,
                     col_ptr, edge_row, gh, dis, seqs, agg2, b_total, slen);
  hipLaunchKernelGGL(k_tail, dim3((b_total + 31) / 32), dim3(256), 0, stream,
                     agg2, wt + (size_t)(T + 1) * 16384, dis, gcnB + 128,
                     seqs, label, predW, predB, out_logits, out_label,
                     b_total, C, slen);
}

// Round 14
// 243.363 us; speedup vs baseline: 1.1374x; 1.0317x over previous
//
#include <hip/hip_runtime.h>
#include <hip/hip_bf16.h>

// ---------------------------------------------------------------------------
// HINormer forward, bf16+MFMA multi-kernel (R14).
// R13 lesson: gather-first commutation was perf-flat and cost 100x accuracy
// margin (absmax 0.25 vs 0.002). Reverted to R8 ordering:
//   gh0 = x@fcW[type]+fcB ; xws=(gh@W)*dis ; gh=relu((xws_c+sum xws_r)*dis+b)
// New vs R8: LDS-transpose epilogue in k_fc / k_gemm_scale. The MFMA C-layout
// was emitting 2B scattered stores -> 2.4-3.8x HBM write amplification
// (WRITE_SIZE 31/49MB vs 12.8 ideal). Results now staged through the dead
// smem_wt region and written as coalesced 16B row stores. 8 launches.
// ---------------------------------------------------------------------------

typedef __attribute__((ext_vector_type(8))) short short8;   // 8 bf16
typedef __attribute__((ext_vector_type(4))) float f32x4;
typedef unsigned short u16;

__device__ __forceinline__ float bf2f(u16 u) {
  union { float f; unsigned int i; } v; v.i = (unsigned int)u << 16; return v.f;
}
__device__ __forceinline__ u16 f2bf(float f) {
  union { float f; unsigned int i; } v; v.f = f;
  return (u16)((v.i + 0x7FFF + ((v.i >> 16) & 1)) >> 16);
}

#define NPB 128
#define SWZ(row, byte) ((byte) ^ (((row) & 15) << 4))

// ---- P0: weight transpose/cast + zero ecnt/cnt -----------------------------
__global__ void k_prep(const float* __restrict__ fcW, const float* __restrict__ gcnW,
                       u16* __restrict__ wt, int* __restrict__ ecnt,
                       int* __restrict__ cnt, int T, int wt_total, int n) {
  const int gt = blockIdx.x * 256 + threadIdx.x;
  const int GT = gridDim.x * 256;
  for (int i = gt; i < wt_total; i += GT) {
    int m = i >> 14, dk = i & 16383, d = dk >> 7, k = dk & 127;
    const float* src = (m < T) ? (fcW + ((size_t)m << 14)) : (gcnW + ((size_t)(m - T) << 14));
    wt[i] = f2bf(src[k * 128 + d]);
  }
  for (int i = gt; i < n; i += GT) ecnt[i] = 0;
  if (gt == 0) *cnt = 0;
}

// stage a [128 x 128] bf16 tile into swizzled LDS; rows >= rows_valid zeroed.
__device__ __forceinline__ void stage_tile_bf16(char* smem, const u16* __restrict__ gsrc,
                                                int rows_valid, int t) {
  int row = t >> 1;
  int h = (t & 1) * 64;
  int byte0 = row * 256 + h * 2;
  if (row < rows_valid) {
    const u16* src = gsrc + (size_t)row * 128 + h;
#pragma unroll
    for (int j = 0; j < 8; ++j) {
      short8 v = *(const short8*)(src + j * 8);
      *(short8*)(smem + SWZ(row, byte0 + j * 16)) = v;
    }
  } else {
    short8 z = (short8){0, 0, 0, 0, 0, 0, 0, 0};
#pragma unroll
    for (int j = 0; j < 8; ++j)
      *(short8*)(smem + SWZ(row, byte0 + j * 16)) = z;
  }
}

// 4 waves; wave w covers output cols [w*32, w*32+32). B preloaded from LDS
// (32 VGPR), A streamed from LDS: 8 ds_read : 16 MFMA per k-slice.
__device__ __forceinline__ void mfma_core128(const char* xs, const char* wt, int t,
                                             f32x4 acc[8][2]) {
  const int lane = t & 63, w = t >> 6;
  const int lr = lane & 15, lk = lane >> 4;
  short8 bfrag[4][2];
#pragma unroll
  for (int ks = 0; ks < 4; ++ks) {
    int kb = ks * 64 + lk * 16;
#pragma unroll
    for (int ch = 0; ch < 2; ++ch) {
      int row = w * 32 + ch * 16 + lr;
      bfrag[ks][ch] = *(const short8*)(wt + SWZ(row, row * 256 + kb));
    }
  }
#pragma unroll
  for (int ks = 0; ks < 4; ++ks) {
    int kb = ks * 64 + lk * 16;
    short8 a[8];
#pragma unroll
    for (int rg = 0; rg < 8; ++rg) {
      int row = rg * 16 + lr;
      a[rg] = *(const short8*)(xs + SWZ(row, row * 256 + kb));
    }
#pragma unroll
    for (int rg = 0; rg < 8; ++rg)
#pragma unroll
      for (int ch = 0; ch < 2; ++ch)
        acc[rg][ch] = __builtin_amdgcn_mfma_f32_16x16x32_bf16(a[rg], bfrag[ks][ch],
                                                              acc[rg][ch], 0, 0, 0);
  }
}

// ---- k_fc (+ degree count piggyback): gh0 = x @ fcW[type] + fcB ------------
__global__ __launch_bounds__(256) void k_fc(const float* __restrict__ x,
                                            const int* __restrict__ node_type,
                                            const u16* __restrict__ wt_fc,
                                            const float* __restrict__ fcB,
                                            u16* __restrict__ gh, int n_nodes,
                                            const int* __restrict__ col,
                                            int* __restrict__ ecnt, int e_edges) {
  __shared__ char smem[65536];
  char* smem_xs = smem;
  char* smem_wt = smem + 32768;
  const int t = threadIdx.x;
  const int nbase = blockIdx.x * NPB;
  const int nend = min(nbase + NPB, n_nodes);
  const int t0 = node_type[nbase];
  const int t1 = node_type[nend - 1];   // sorted types

  {
    int row = t >> 1;
    int h = (t & 1) * 64;
    int node = nbase + row;
    int byte0 = row * 256 + h * 2;
    if (node < n_nodes) {
      const float4* src = (const float4*)(x + (size_t)node * 128 + h);
#pragma unroll
      for (int j = 0; j < 8; ++j) {
        float4 a4 = src[j * 2], b4 = src[j * 2 + 1];
        u16 tmp[8] = {f2bf(a4.x), f2bf(a4.y), f2bf(a4.z), f2bf(a4.w),
                      f2bf(b4.x), f2bf(b4.y), f2bf(b4.z), f2bf(b4.w)};
        *(short8*)(smem_xs + SWZ(row, byte0 + j * 16)) = *(short8*)tmp;
      }
    } else {
      short8 z = (short8){0, 0, 0, 0, 0, 0, 0, 0};
#pragma unroll
      for (int j = 0; j < 8; ++j)
        *(short8*)(smem_xs + SWZ(row, byte0 + j * 16)) = z;
    }
  }

  const int lane = t & 63, w = t >> 6;
  const int lr = lane & 15, lk = lane >> 4;

  for (int tt = t0; tt <= t1; ++tt) {
    __syncthreads();  // xs staged (iter 0) / epilogue LDS reads done (iter >0)
    stage_tile_bf16(smem_wt, wt_fc + ((size_t)tt << 14), 128, t);
    __syncthreads();

    f32x4 acc[8][2];
#pragma unroll
    for (int rg = 0; rg < 8; ++rg)
#pragma unroll
      for (int ch = 0; ch < 2; ++ch) acc[rg][ch] = (f32x4){0.f, 0.f, 0.f, 0.f};
    mfma_core128(smem_xs, smem_wt, t, acc);

    // epilogue: bias in f32, bf16 into dead smem_wt (transposed), then
    // coalesced 16B row stores (fix 2.4x write amplification)
    __syncthreads();  // all bfrag reads of smem_wt complete
    u16* tb = (u16*)smem_wt;
    float bv0 = fcB[tt * 128 + w * 32 + lr];
    float bv1 = fcB[tt * 128 + w * 32 + 16 + lr];
#pragma unroll
    for (int rg = 0; rg < 8; ++rg) {
#pragma unroll
      for (int reg = 0; reg < 4; ++reg) {
        int row = rg * 16 + lk * 4 + reg;
        tb[row * 128 + w * 32 + lr]      = f2bf(acc[rg][0][reg] + bv0);
        tb[row * 128 + w * 32 + 16 + lr] = f2bf(acc[rg][1][reg] + bv1);
      }
    }
    __syncthreads();
    {
      int row = t >> 1;
      int h = (t & 1) * 64;
      int node = nbase + row;
      if (node < n_nodes && node_type[node] == tt) {
        u16* dst = gh + (size_t)node * 128 + h;
        const u16* srcp = tb + row * 128 + h;
#pragma unroll
        for (int j = 0; j < 8; ++j)
          *(short8*)(dst + j * 8) = *(const short8*)(srcp + j * 8);
      }
    }
  }

  // piggyback: in-degree count (independent; consumed next launch)
  const int gt = blockIdx.x * 256 + t;
  const int GT = gridDim.x * 256;
  for (int i = gt; i < e_edges; i += GT) atomicAdd(&ecnt[col[i]], 1);
}

// ---- k_gemm_scale (+ optional CSR fill piggyback): xws = (gh@W)*dis --------
__global__ __launch_bounds__(256) void k_gemm_scale(const u16* __restrict__ ghin,
                                                    const u16* __restrict__ wtg,
                                                    const float* __restrict__ dis,
                                                    u16* __restrict__ xws, int n_nodes,
                                                    const int* __restrict__ row,
                                                    const int* __restrict__ col,
                                                    int* __restrict__ cursor,
                                                    int* __restrict__ edge_row,
                                                    int e_edges, int do_fill) {
  __shared__ char smem[65536];
  char* smem_xs = smem;
  char* smem_wt = smem + 32768;
  const int t = threadIdx.x;
  const int nbase = blockIdx.x * NPB;

  stage_tile_bf16(smem_xs, ghin + (size_t)nbase * 128, min(n_nodes - nbase, NPB), t);
  stage_tile_bf16(smem_wt, wtg, 128, t);
  __syncthreads();

  f32x4 acc[8][2];
#pragma unroll
  for (int rg = 0; rg < 8; ++rg)
#pragma unroll
    for (int ch = 0; ch < 2; ++ch) acc[rg][ch] = (f32x4){0.f, 0.f, 0.f, 0.f};
  mfma_core128(smem_xs, smem_wt, t, acc);

  const int lane = t & 63, w = t >> 6;
  const int lr = lane & 15, lk = lane >> 4;

  // epilogue: scale by dis (f32, single rounding), stage via dead smem_wt,
  // coalesced 16B row stores (fix 3.8x write amplification)
  __syncthreads();
  u16* tb = (u16*)smem_wt;
#pragma unroll
  for (int rg = 0; rg < 8; ++rg) {
    // dis for 4 consecutive rows (may over-read past n into ws scratch; those
    // rows are masked at the global store)
    float4 d4 = *(const float4*)(dis + nbase + rg * 16 + lk * 4);
#pragma unroll
    for (int reg = 0; reg < 4; ++reg) {
      float dv = (&d4.x)[reg];
      int row = rg * 16 + lk * 4 + reg;
      tb[row * 128 + w * 32 + lr]      = f2bf(acc[rg][0][reg] * dv);
      tb[row * 128 + w * 32 + 16 + lr] = f2bf(acc[rg][1][reg] * dv);
    }
  }
  __syncthreads();
  {
    int rowi = t >> 1;
    int h = (t & 1) * 64;
    int node = nbase + rowi;
    if (node < n_nodes) {
      u16* dst = xws + (size_t)node * 128 + h;
      const u16* srcp = tb + rowi * 128 + h;
#pragma unroll
      for (int j = 0; j < 8; ++j)
        *(short8*)(dst + j * 8) = *(const short8*)(srcp + j * 8);
    }
  }

  if (do_fill) {  // piggyback: CSR fill (needs cursor from scan3; feeds gather)
    const int gt = blockIdx.x * 256 + t;
    const int GT = gridDim.x * 256;
    for (int i = gt; i < e_edges; i += GT) {
      int c = col[i];
      int pos = atomicAdd(&cursor[c], 1);
      edge_row[pos] = row[i];
    }
  }
}

// ---- scan1: per-chunk scan + dis; last block scans the partials ------------
__global__ __launch_bounds__(256) void k_scan1(const int* __restrict__ ecnt,
                                               int* __restrict__ scanex,
                                               int* __restrict__ partials,
                                               float* __restrict__ dis,
                                               int* __restrict__ cnt, int n) {
  __shared__ int s[256];
  __shared__ int lastflag;
  const int t = threadIdx.x;
  const int i = blockIdx.x * 256 + t;
  int v = (i < n) ? ecnt[i] : 0;
  s[t] = v;
  __syncthreads();
  for (int off = 1; off < 256; off <<= 1) {
    int add = (t >= off) ? s[t - off] : 0;
    __syncthreads();
    s[t] += add;
    __syncthreads();
  }
  if (i < n) {
    scanex[i] = s[t] - v;
    dis[i] = rsqrtf((float)(v + 1));
  }
  if (t == 255) partials[blockIdx.x] = s[t];
  __threadfence();
  if (t == 0) lastflag = (atomicAdd(cnt, 1) == gridDim.x - 1) ? 1 : 0;
  __syncthreads();
  if (lastflag) {
    __threadfence();
    int np = gridDim.x;
    int pv = (t < np) ? partials[t] : 0;
    s[t] = pv;
    __syncthreads();
    for (int off = 1; off < 256; off <<= 1) {
      int add = (t >= off) ? s[t - off] : 0;
      __syncthreads();
      s[t] += add;
      __syncthreads();
    }
    if (t < np) partials[t] = s[t] - pv;
  }
}

__global__ void k_scan3(const int* __restrict__ scanex, const int* __restrict__ partials,
                        int* __restrict__ col_ptr, int* __restrict__ cursor,
                        int n, int e_total) {
  int i = blockIdx.x * 256 + threadIdx.x;
  if (i < n) {
    int p = scanex[i] + partials[i >> 8];
    col_ptr[i] = p;
    cursor[i] = p;
  }
  if (i == 0) col_ptr[n] = e_total;
}

// ---- fused gather + finalize ------------------------------------------------
__device__ __forceinline__ void gather_node(int node, const int* __restrict__ col_ptr,
                                            const int* __restrict__ edge_row,
                                            const u16* __restrict__ xws,
                                            const float* __restrict__ dis,
                                            const float* __restrict__ bias,
                                            u16* __restrict__ dst, int lane) {
  const int g = lane & 15;
  const int s = lane >> 4;
  float acc[8] = {0.f, 0.f, 0.f, 0.f, 0.f, 0.f, 0.f, 0.f};
  if (s == 0) {  // self loop
    short8 v = *(const short8*)(xws + (size_t)node * 128 + g * 8);
#pragma unroll
    for (int j = 0; j < 8; ++j) acc[j] = bf2f((u16)v[j]);
  }
  const int e0 = col_ptr[node], e1 = col_ptr[node + 1];
  for (int e = e0 + s; e < e1; e += 4) {
    int r = edge_row[e];
    short8 v = *(const short8*)(xws + (size_t)r * 128 + g * 8);
#pragma unroll
    for (int j = 0; j < 8; ++j) acc[j] += bf2f((u16)v[j]);
  }
#pragma unroll
  for (int j = 0; j < 8; ++j) {
    acc[j] += __shfl_xor(acc[j], 16);
    acc[j] += __shfl_xor(acc[j], 32);
  }
  if (s == 0) {
    float ds = dis[node];
    u16 o[8];
#pragma unroll
    for (int j = 0; j < 8; ++j)
      o[j] = f2bf(fmaxf(acc[j] * ds + bias[g * 8 + j], 0.f));
    *(short8*)(dst + g * 8) = *(short8*)o;
  }
}

__global__ __launch_bounds__(256) void k_gather(const int* __restrict__ col_ptr,
                                                const int* __restrict__ edge_row,
                                                const u16* __restrict__ xws,
                                                const float* __restrict__ dis,
                                                const float* __restrict__ bias,
                                                u16* __restrict__ gh, int n_nodes) {
  const int t = threadIdx.x;
  const int node = blockIdx.x * 4 + (t >> 6);
  if (node >= n_nodes) return;
  gather_node(node, col_ptr, edge_row, xws, dis, bias,
              gh + (size_t)node * 128, t & 63);
}

// ---- last layer: gather only ego nodes, then predict in-kernel -------------
__global__ __launch_bounds__(256) void k_egopred(const int* __restrict__ col_ptr,
                                                 const int* __restrict__ edge_row,
                                                 const u16* __restrict__ xws,
                                                 const float* __restrict__ dis,
                                                 const float* __restrict__ bias,
                                                 const int* __restrict__ seqs,
                                                 const int* __restrict__ label,
                                                 const float* __restrict__ predW,
                                                 const float* __restrict__ predB,
                                                 float* __restrict__ out,
                                                 float* __restrict__ out_label,
                                                 int b_total, int n_classes, int slen) {
  __shared__ u16 buf[4][128];
  const int t = threadIdx.x;
  const int w = t >> 6, lane = t & 63;
  const int b = blockIdx.x * 4 + w;
  int node = -1;
  if (b < b_total) {
    node = seqs[(size_t)b * slen];
    gather_node(node, col_ptr, edge_row, xws, dis, bias, &buf[w][0], lane);
  }
  __syncthreads();
  if (b < b_total) {
    const int c = lane & 15;     // class (n_classes == 16)
    const int q = lane >> 4;     // k-chunk 0..3
    float s = 0.f;
#pragma unroll 8
    for (int k = q * 32; k < q * 32 + 32; ++k)
      s += bf2f(buf[w][k]) * predW[k * n_classes + c];
    s += __shfl_xor(s, 16);
    s += __shfl_xor(s, 32);
    if (q == 0) out[(size_t)b * n_classes + c] = s + predB[c];
    if (lane == 0) out_label[b] = (float)label[node];
  }
}

extern "C" void kernel_launch(void* const* d_in, const int* in_sizes, int n_in,
                              void* d_out, int out_size, void* d_ws, size_t ws_size,
                              hipStream_t stream) {
  const float* x     = (const float*)d_in[0];
  const int*   label = (const int*)d_in[1];
  const int*   seqs  = (const int*)d_in[2];
  const int*   edge  = (const int*)d_in[3];
  const int*   ntype = (const int*)d_in[4];
  const float* fcW   = (const float*)d_in[5];
  const float* fcB   = (const float*)d_in[6];
  const float* gcnW  = (const float*)d_in[7];
  const float* gcnB  = (const float*)d_in[8];
  const float* predW = (const float*)d_in[12];
  const float* predB = (const float*)d_in[13];

  const int n = in_sizes[0] / 128;          // 50000
  const int e = in_sizes[3] / 2;            // 600000
  const int T = in_sizes[5] / (128 * 128);  // 4
  const int L = in_sizes[8] / 128;          // 2
  const int C = in_sizes[13];               // 16
  const int slen = 16;
  const int b_total = in_sizes[2] / slen;   // 2048

  const int* row = edge;
  const int* col = edge + e;

  char* ws = (char*)d_ws;
  const size_t node_bf = (size_t)n * 128 * sizeof(u16);
  u16*   gh      = (u16*)ws;                 ws += node_bf;
  u16*   xws     = (u16*)ws;                 ws += node_bf;
  u16*   wt      = (u16*)ws;                 ws += (size_t)(T + L) * 16384 * 2;
  float* dis     = (float*)ws;               ws += (size_t)n * 4;
  int*   ecnt    = (int*)ws;                 ws += (size_t)n * 4;
  int*   scanex  = (int*)ws;                 ws += (size_t)n * 4;
  int*   col_ptr = (int*)ws;                 ws += (size_t)(n + 16) * 4;
  int*   cursor  = (int*)ws;                 ws += (size_t)n * 4;
  int*   partial = (int*)ws;                 ws += 1024 * 4;
  int*   cnt     = (int*)ws;                 ws += 64;
  int*   edge_row= (int*)ws;                 ws += (size_t)e * 4;

  float* out_logits = (float*)d_out;
  float* out_label  = out_logits + (size_t)b_total * C;

  const int nb = (n + NPB - 1) / NPB;       // 391
  const int nscan = (n + 255) / 256;        // 196
  const int wt_total = (T + L) * 16384;

  hipLaunchKernelGGL(k_prep, dim3(384), dim3(256), 0, stream,
                     fcW, gcnW, wt, ecnt, cnt, T, wt_total, n);
  hipLaunchKernelGGL(k_fc, dim3(nb), dim3(256), 0, stream,
                     x, ntype, wt, fcB, gh, n, col, ecnt, e);
  hipLaunchKernelGGL(k_scan1, dim3(nscan), dim3(256), 0, stream,
                     ecnt, scanex, partial, dis, cnt, n);
  hipLaunchKernelGGL(k_scan3, dim3(nscan), dim3(256), 0, stream,
                     scanex, partial, col_ptr, cursor, n, e);

  for (int l = 0; l < L; ++l) {
    hipLaunchKernelGGL(k_gemm_scale, dim3(nb), dim3(256), 0, stream,
                       gh, wt + (size_t)(T + l) * 16384, dis, xws, n,
                       row, col, cursor, edge_row, e, (l == 0) ? 1 : 0);
    if (l < L - 1) {
      hipLaunchKernelGGL(k_gather, dim3((n + 3) / 4), dim3(256), 0, stream,
                         col_ptr, edge_row, xws, dis, gcnB + (size_t)l * 128, gh, n);
    } else {
      hipLaunchKernelGGL(k_egopred, dim3((b_total + 3) / 4), dim3(256), 0, stream,
                         col_ptr, edge_row, xws, dis, gcnB + (size_t)l * 128,
                         seqs, label, predW, predB, out_logits, out_label,
                         b_total, C, slen);
    }
  }
}